// Round 2
// baseline (528.894 us; speedup 1.0000x reference)
//
#include <hip/hip_runtime.h>

typedef unsigned short u16;
typedef __attribute__((ext_vector_type(8))) short short8;
typedef __attribute__((ext_vector_type(4))) float floatx4;

#define NB 64
#define HH 56
#define WW_ 56
#define CC 128
#define NHEADS 4
#define WS2 49
#define PAD 4      // P_T = P_L = 4
#define HID 512

__device__ __forceinline__ float bf2f(u16 u){ return __uint_as_float(((unsigned)u)<<16); }
__device__ __forceinline__ u16 f2bf(float f){
  unsigned u = __float_as_uint(f);
  return (u16)((u + 0x7FFFu + ((u>>16)&1u)) >> 16);
}

// ---------------------------------------------------------------------------
// prep: fc1_w (C,HID) f32 -> bf16 (HID,C);  fc2_w (HID,C) f32 -> bf16 (C,HID)
//       spatial_w [h][i][j] f32 -> [h][j][i] f32, i-stride padded to 52
// ---------------------------------------------------------------------------
__global__ __launch_bounds__(256) void prep_k(
    const float* __restrict__ fc1_w, const float* __restrict__ fc2_w,
    const float* __restrict__ sw,
    u16* __restrict__ fc1_wT, u16* __restrict__ fc2_wT, float* __restrict__ swT)
{
  int tid = blockIdx.x*256 + threadIdx.x;
  int nth = gridDim.x * 256;
  for (int idx = tid; idx < HID*CC; idx += nth) {
    int n = idx >> 7, k = idx & 127;
    fc1_wT[idx] = f2bf(fc1_w[k*HID + n]);
  }
  for (int idx = tid; idx < CC*HID; idx += nth) {
    int c = idx >> 9, h = idx & 511;
    fc2_wT[idx] = f2bf(fc2_w[h*CC + c]);
  }
  for (int idx = tid; idx < NHEADS*WS2*52; idx += nth) {
    int i = idx % 52; int rest = idx / 52; int j = rest % WS2; int hd = rest / WS2;
    swT[idx] = (i < WS2) ? sw[(hd*WS2 + i)*WS2 + j] : 0.f;
  }
}

// ---------------------------------------------------------------------------
// winmix: fused LN1 + shifted-window per-head token mix + residual -> x2 (f32)
// one block per (batch, window). Windows tile the padded 63x63 grid exactly;
// padding positions contribute xn == 0 (reference pads AFTER LN); cropped
// outputs are simply not written.
// ---------------------------------------------------------------------------
__global__ __launch_bounds__(256) void winmix_k(
    const float* __restrict__ x, const float* __restrict__ g1, const float* __restrict__ b1,
    const float* __restrict__ swT, const float* __restrict__ sb,
    float* __restrict__ x2)
{
  __shared__ float wlds[NHEADS*WS2*52];   // 40768 B, [h][j][i] i-stride 52
  __shared__ u16 xn[WS2*CC];              // 12544 B, LN output (bf16) per window pos
  int tid = threadIdx.x;
  int b = blockIdx.x / 81; int wi = blockIdx.x - b*81;
  int wh = wi / 9, wwn = wi - wh*9;

  { // stage spatial weights (contiguous f32x4 copy)
    const float4* src = (const float4*)swT;
    float4* dst = (float4*)wlds;
    for (int i4 = tid; i4 < NHEADS*WS2*13; i4 += 256) dst[i4] = src[i4];
  }

  // LN per window position: one wave per position, 2 channels/lane
  int wvid = tid >> 6, lane = tid & 63;
  float gl0 = g1[lane], gl1 = g1[lane+64];
  float bl0 = b1[lane], bl1 = b1[lane+64];
  for (int jj = wvid; jj < WS2; jj += 4) {
    int jr = jj / 7, jc = jj - jr*7;
    int pr = wh*7 + jr - PAD, pc = wwn*7 + jc - PAD;
    bool valid = (pr>=0) & (pr<HH) & (pc>=0) & (pc<WW_);
    float v0 = 0.f, v1 = 0.f;
    const float* px = x + ((size_t)((b*HH + pr)*WW_ + pc))*CC;
    if (valid) { v0 = px[lane]; v1 = px[lane+64]; }
    float s = v0 + v1, ss = v0*v0 + v1*v1;
    #pragma unroll
    for (int o = 32; o > 0; o >>= 1) { s += __shfl_xor(s, o); ss += __shfl_xor(ss, o); }
    float mu = s * (1.f/128.f);
    float var = ss * (1.f/128.f) - mu*mu;
    float rs = rsqrtf(var + 1e-5f);
    u16 o0 = 0, o1 = 0;
    if (valid) {
      o0 = f2bf((v0 - mu)*rs*gl0 + bl0);
      o1 = f2bf((v1 - mu)*rs*gl1 + bl1);
    }
    xn[jj*CC + lane]      = o0;
    xn[jj*CC + lane + 64] = o1;
  }
  __syncthreads();

  // token mixing: thread = (i-block of 8) x (4 channels)
  int cg = tid & 31, ig = tid >> 5;
  int c0 = cg*4; int hd = c0 >> 5;
  int ibase = ig*8;
  float acc[8][4];
  #pragma unroll
  for (int ii = 0; ii < 8; ii++) {
    int i = ibase + ii;
    float bb = (i < WS2) ? sb[hd*WS2 + i] : 0.f;
    #pragma unroll
    for (int k = 0; k < 4; k++) acc[ii][k] = bb;
  }
  const float* wrow = wlds + hd*(WS2*52) + ibase;
  for (int j = 0; j < WS2; j++) {
    ushort4 xv = *(const ushort4*)&xn[j*CC + c0];
    float v0 = bf2f(xv.x), v1 = bf2f(xv.y), v2 = bf2f(xv.z), v3 = bf2f(xv.w);
    float4 wa = *(const float4*)(wrow + j*52);
    float4 wb = *(const float4*)(wrow + j*52 + 4);
    float wr[8] = {wa.x,wa.y,wa.z,wa.w,wb.x,wb.y,wb.z,wb.w};
    #pragma unroll
    for (int ii = 0; ii < 8; ii++) {
      acc[ii][0] += wr[ii]*v0; acc[ii][1] += wr[ii]*v1;
      acc[ii][2] += wr[ii]*v2; acc[ii][3] += wr[ii]*v3;
    }
  }
  // residual add + write (skip cropped positions)
  #pragma unroll
  for (int ii = 0; ii < 8; ii++) {
    int i = ibase + ii;
    if (i >= WS2) break;
    int ir = i / 7, ic = i - ir*7;
    int orow = wh*7 + ir - PAD, ocol = wwn*7 + ic - PAD;
    if (orow>=0 && orow<HH && ocol>=0 && ocol<WW_) {
      size_t base = ((size_t)((b*HH + orow)*WW_ + ocol))*CC + c0;
      float4 xr = *(const float4*)&x[base];
      float4 o;
      o.x = xr.x + acc[ii][0];
      o.y = xr.y + acc[ii][1];
      o.z = xr.z + acc[ii][2];
      o.w = xr.w + acc[ii][3];
      *(float4*)&x2[base] = o;
    }
  }
}

// ---------------------------------------------------------------------------
// mlp: x2 -> LN2 -> fc1+GELU -> fc2 -> +x2 (in place, f32 I/O, bf16 MFMA)
// Block = 64 tokens x 256 threads (4 waves, 16 token-rows each).
// HID processed in 8 chunks of 64; H round-trips through LDS (D-layout ->
// A-layout transform). All LDS strides = 4 dwords mod 32.
// ---------------------------------------------------------------------------
__global__ __launch_bounds__(256) void mlp_k(
    float* __restrict__ xio,
    const float* __restrict__ g2, const float* __restrict__ b2,
    const u16* __restrict__ fc1_wT, const float* __restrict__ fc1_b,
    const u16* __restrict__ fc2_wT, const float* __restrict__ fc2_b)
{
  __shared__ u16 Albs[64*136];   // LN2(x2) tile   [m][k=C]    17408 B
  __shared__ u16 B1[64*136];     // fc1_wT chunk   [n][k=C]    17408 B
  __shared__ u16 Ht[64*72];      // GELU(h) chunk  [m][k=hid]   9216 B
  __shared__ u16 B2[128*72];     // fc2_wT chunk   [n=C][k=hid] 18432 B
  int tid = threadIdx.x;
  int wvid = tid >> 6, lane = tid & 63;
  int ln = lane & 15, qd = lane >> 4;
  size_t tokbase = (size_t)blockIdx.x * 64;

  float gl0 = g2[lane], gl1 = g2[lane+64];
  float bl0 = b2[lane], bl1 = b2[lane+64];
  for (int t = wvid; t < 64; t += 4) {
    const float* px = xio + (tokbase + t)*CC;
    float v0 = px[lane], v1 = px[lane+64];
    float s = v0+v1, ss = v0*v0+v1*v1;
    #pragma unroll
    for (int o = 32; o > 0; o >>= 1) { s += __shfl_xor(s,o); ss += __shfl_xor(ss,o); }
    float mu = s*(1.f/128.f), var = ss*(1.f/128.f) - mu*mu;
    float rs = rsqrtf(var + 1e-5f);
    Albs[t*136 + lane]      = f2bf((v0-mu)*rs*gl0 + bl0);
    Albs[t*136 + lane + 64] = f2bf((v1-mu)*rs*gl1 + bl1);
  }

  floatx4 oacc[8];
  #pragma unroll
  for (int nt = 0; nt < 8; nt++) oacc[nt] = (floatx4){0.f,0.f,0.f,0.f};

  int m0 = wvid*16;
  for (int ch = 0; ch < 8; ch++) {
    { // stage B1 (64x128) and B2 (128x64) chunks, 16B vector loads
      const uint4* src = (const uint4*)fc1_wT;      // row = 128 u16 = 16 uint4
      uint4* dst = (uint4*)B1;
      #pragma unroll
      for (int r = 0; r < 4; r++) {
        int idx = tid + r*256;
        int n = idx >> 4, q = idx & 15;
        dst[n*17 + q] = src[(ch*64 + n)*16 + q];
      }
      const uint4* src2 = (const uint4*)fc2_wT;     // row = 512 u16 = 64 uint4
      uint4* dst2 = (uint4*)B2;
      #pragma unroll
      for (int r = 0; r < 4; r++) {
        int idx = tid + r*256;
        int n = idx >> 3, q = idx & 7;
        dst2[n*9 + q] = src2[n*64 + ch*8 + q];
      }
    }
    __syncthreads();
    // gemm1: H-chunk[m0..m0+16)[0..64) = A @ B1^T, + bias, exact GELU
    {
      short8 av1[4];
      #pragma unroll
      for (int ks = 0; ks < 4; ks++)
        av1[ks] = *(const short8*)&Albs[(m0 + ln)*136 + ks*32 + qd*8];
      #pragma unroll
      for (int nt = 0; nt < 4; nt++) {
        floatx4 a1 = {0.f,0.f,0.f,0.f};
        #pragma unroll
        for (int ks = 0; ks < 4; ks++) {
          short8 bv = *(const short8*)&B1[(nt*16 + ln)*136 + ks*32 + qd*8];
          a1 = __builtin_amdgcn_mfma_f32_16x16x32_bf16(av1[ks], bv, a1, 0, 0, 0);
        }
        int n = nt*16 + ln;
        float bias = fc1_b[ch*64 + n];
        #pragma unroll
        for (int r = 0; r < 4; r++) {
          float hv = a1[r] + bias;
          hv = 0.5f*hv*(1.f + erff(hv*0.70710678118f));
          Ht[(m0 + qd*4 + r)*72 + n] = f2bf(hv);   // D-layout -> A-layout via LDS
        }
      }
    }
    __syncthreads();
    // gemm2: out += H-chunk @ B2^T
    {
      short8 av2[2];
      #pragma unroll
      for (int ks = 0; ks < 2; ks++)
        av2[ks] = *(const short8*)&Ht[(m0 + ln)*72 + ks*32 + qd*8];
      #pragma unroll
      for (int nt = 0; nt < 8; nt++) {
        floatx4 acc = oacc[nt];
        #pragma unroll
        for (int ks = 0; ks < 2; ks++) {
          short8 bv = *(const short8*)&B2[(nt*16 + ln)*72 + ks*32 + qd*8];
          acc = __builtin_amdgcn_mfma_f32_16x16x32_bf16(av2[ks], bv, acc, 0, 0, 0);
        }
        oacc[nt] = acc;
      }
    }
    __syncthreads();
  }
  // epilogue: + fc2 bias + residual (x2 re-read from xio), in-place write
  #pragma unroll
  for (int nt = 0; nt < 8; nt++) {
    int n = nt*16 + ln;
    float bb = fc2_b[n];
    #pragma unroll
    for (int r = 0; r < 4; r++) {
      size_t tok = tokbase + m0 + qd*4 + r;
      float res = xio[tok*CC + n];
      xio[tok*CC + n] = res + oacc[nt][r] + bb;
    }
  }
}

extern "C" void kernel_launch(void* const* d_in, const int* in_sizes, int n_in,
                              void* d_out, int out_size, void* d_ws, size_t ws_size,
                              hipStream_t stream) {
  const float* x     = (const float*)d_in[0];
  const float* g1    = (const float*)d_in[1];
  const float* b1    = (const float*)d_in[2];
  const float* sw    = (const float*)d_in[3];
  const float* sb    = (const float*)d_in[4];
  const float* g2    = (const float*)d_in[5];
  const float* b2    = (const float*)d_in[6];
  const float* fc1_w = (const float*)d_in[7];
  const float* fc1_b = (const float*)d_in[8];
  const float* fc2_w = (const float*)d_in[9];
  const float* fc2_b = (const float*)d_in[10];
  float* out = (float*)d_out;

  u16* fc1_wT = (u16*)d_ws;                  // 512*128 bf16 (131072 B)
  u16* fc2_wT = fc1_wT + HID*CC;             // 128*512 bf16 (131072 B)
  float* swT  = (float*)(fc2_wT + CC*HID);   // 4*49*52 f32  (40768 B)

  prep_k<<<64, 256, 0, stream>>>(fc1_w, fc2_w, sw, fc1_wT, fc2_wT, swT);
  winmix_k<<<NB*81, 256, 0, stream>>>(x, g1, b1, swT, sb, out);
  mlp_k<<<(NB*HH*WW_)/64, 256, 0, stream>>>(out, g2, b2, fc1_wT, fc1_b, fc2_wT, fc2_b);
}

// Round 3
// 506.356 us; speedup vs baseline: 1.0445x; 1.0445x over previous
//
#include <hip/hip_runtime.h>

typedef unsigned short u16;
typedef __attribute__((ext_vector_type(8))) short short8;
typedef __attribute__((ext_vector_type(4))) float floatx4;

#define NB 64
#define HH 56
#define WW_ 56
#define CC 128
#define NHEADS 4
#define WS2 49
#define PAD 4      // P_T = P_L = 4
#define HID 512

__device__ __forceinline__ float bf2f(u16 u){ return __uint_as_float(((unsigned)u)<<16); }
__device__ __forceinline__ u16 f2bf(float f){
  unsigned u = __float_as_uint(f);
  return (u16)((u + 0x7FFFu + ((u>>16)&1u)) >> 16);
}
// tanh-approx GELU in sigmoid form: x * sigmoid(1.5957691*x*(1+0.044715*x^2))
__device__ __forceinline__ float gelu_f(float x){
  float u2 = x*(1.5957691216f + 0.0713548162f*x*x);
  return x / (1.f + __expf(-u2));
}
// element-wise fragment load; compiler merges to the widest provably-aligned DS op
__device__ __forceinline__ short8 ld_frag(const u16* p){
  short8 v;
  #pragma unroll
  for (int e = 0; e < 8; e++) v[e] = (short)p[e];
  return v;
}

// ---------------------------------------------------------------------------
// prep: fc1_w (C,HID) f32 -> bf16 [HID][C];  fc2_w (HID,C) f32 -> bf16 [C][HID]
//       spatial_w [h][i][j] f32 -> bf16 [h][i(64)][j(stride 68)], zero-padded
// ---------------------------------------------------------------------------
__global__ __launch_bounds__(256) void prep_k(
    const float* __restrict__ fc1_w, const float* __restrict__ fc2_w,
    const float* __restrict__ sw,
    u16* __restrict__ fc1_wT, u16* __restrict__ fc2_wT, u16* __restrict__ swT)
{
  int tid = blockIdx.x*256 + threadIdx.x;
  int nth = gridDim.x * 256;
  for (int idx = tid; idx < HID*CC; idx += nth) {
    int n = idx >> 7, k = idx & 127;
    fc1_wT[idx] = f2bf(fc1_w[k*HID + n]);
  }
  for (int idx = tid; idx < CC*HID; idx += nth) {
    int c = idx >> 9, h = idx & 511;
    fc2_wT[idx] = f2bf(fc2_w[h*CC + c]);
  }
  for (int idx = tid; idx < NHEADS*64*68; idx += nth) {
    int hd = idx / (64*68); int rem = idx - hd*64*68;
    int i = rem / 68, j = rem - i*68;
    swT[idx] = (i < WS2 && j < WS2) ? f2bf(sw[(hd*WS2 + i)*WS2 + j]) : (u16)0;
  }
}

// ---------------------------------------------------------------------------
// winmix: fused LN1 + shifted-window token mix (MFMA) + residual -> x2 (f32)
// one block per (batch, window); wave = head. W: A-operand [i][j] bf16,
// LN out transposed to [c][j] bf16 so B-fragments are j-contiguous.
// Per head: D[i,c] = sum_j W[i][j]*xn[j][c], 4 m-tiles x 2 n-tiles x 2 ks.
// ---------------------------------------------------------------------------
__global__ __launch_bounds__(256, 2) void winmix_k(
    const float* __restrict__ x, const float* __restrict__ g1, const float* __restrict__ b1,
    const u16* __restrict__ swT, const float* __restrict__ sb,
    float* __restrict__ x2)
{
  __shared__ u16 wl[NHEADS*64*68];   // 34816 B, bf16 W [hd][i][j] stride 68
  __shared__ u16 xnt[CC*66];         // 16896 B, bf16 LN-out [c][j] stride 66
  __shared__ float sbl[NHEADS*WS2];  // 784 B
  int tid = threadIdx.x;
  int wvid = tid >> 6, lane = tid & 63;
  int ln = lane & 15, qd = lane >> 4;
  int b = blockIdx.x / 81; int wi = blockIdx.x - b*81;
  int wh = wi / 9, wwn = wi - wh*9;

  { // stage spatial weights: 4*64*68 u16 = 4352 uint2, 17 per thread
    const uint2* ws = (const uint2*)swT;
    uint2* wd = (uint2*)wl;
    #pragma unroll
    for (int r = 0; r < 17; r++) wd[tid + r*256] = ws[tid + r*256];
    if (tid < NHEADS*WS2) sbl[tid] = sb[tid];
  }

  // LN per window position (transposed write); jj>=49 writes zeros (K pad)
  float gl0 = g1[lane], gl1 = g1[lane+64];
  float bl0 = b1[lane], bl1 = b1[lane+64];
  for (int jj = wvid; jj < 64; jj += 4) {
    u16 o0 = 0, o1 = 0;
    if (jj < WS2) {
      int jr = jj / 7, jc = jj - jr*7;
      int pr = wh*7 + jr - PAD, pc = wwn*7 + jc - PAD;
      bool valid = (pr>=0) & (pr<HH) & (pc>=0) & (pc<WW_);
      float v0 = 0.f, v1 = 0.f;
      const float* px = x + ((size_t)((b*HH + pr)*WW_ + pc))*CC;
      if (valid) { v0 = px[lane]; v1 = px[lane+64]; }
      float s = v0 + v1, ss = v0*v0 + v1*v1;
      #pragma unroll
      for (int o = 32; o > 0; o >>= 1) { s += __shfl_xor(s, o); ss += __shfl_xor(ss, o); }
      float mu = s * (1.f/128.f);
      float var = ss * (1.f/128.f) - mu*mu;
      float rs = rsqrtf(var + 1e-5f);
      if (valid) {
        o0 = f2bf((v0 - mu)*rs*gl0 + bl0);
        o1 = f2bf((v1 - mu)*rs*gl1 + bl1);
      }
    }
    xnt[lane*66 + jj]      = o0;
    xnt[(lane+64)*66 + jj] = o1;
  }
  __syncthreads();

  // MFMA token mix: wave = head
  int hd = wvid;
  const u16* wbase = wl + hd*64*68;
  short8 af[4][2];
  #pragma unroll
  for (int mt = 0; mt < 4; mt++)
    #pragma unroll
    for (int ks = 0; ks < 2; ks++)
      af[mt][ks] = ld_frag(&wbase[(mt*16 + ln)*68 + ks*32 + qd*8]);
  short8 bf_[2][2];
  #pragma unroll
  for (int nt = 0; nt < 2; nt++)
    #pragma unroll
    for (int ks = 0; ks < 2; ks++)
      bf_[nt][ks] = ld_frag(&xnt[(hd*32 + nt*16 + ln)*66 + ks*32 + qd*8]);
  floatx4 acc[4][2];
  #pragma unroll
  for (int mt = 0; mt < 4; mt++)
    #pragma unroll
    for (int nt = 0; nt < 2; nt++)
      acc[mt][nt] = (floatx4){0.f,0.f,0.f,0.f};
  #pragma unroll
  for (int ks = 0; ks < 2; ks++)
    #pragma unroll
    for (int mt = 0; mt < 4; mt++)
      #pragma unroll
      for (int nt = 0; nt < 2; nt++)
        acc[mt][nt] = __builtin_amdgcn_mfma_f32_16x16x32_bf16(af[mt][ks], bf_[nt][ks], acc[mt][nt], 0, 0, 0);

  // epilogue: residual add + spatial bias + write (skip pad/cropped)
  #pragma unroll
  for (int mt = 0; mt < 4; mt++) {
    #pragma unroll
    for (int r = 0; r < 4; r++) {
      int i = mt*16 + qd*4 + r;
      if (i < WS2) {
        int ir = i / 7, ic = i - ir*7;
        int orow = wh*7 + ir - PAD, ocol = wwn*7 + ic - PAD;
        if (orow>=0 && orow<HH && ocol>=0 && ocol<WW_) {
          float sbv = sbl[hd*WS2 + i];
          size_t base = ((size_t)((b*HH + orow)*WW_ + ocol))*CC + hd*32;
          #pragma unroll
          for (int nt = 0; nt < 2; nt++) {
            int c = nt*16 + ln;
            x2[base + c] = x[base + c] + acc[mt][nt][r] + sbv;
          }
        }
      }
    }
  }
}

// ---------------------------------------------------------------------------
// mlp: x2 -> LN2 -> fc1+GELU -> fc2 -> +x2 (in-place, f32 I/O, bf16 MFMA)
// 128 tokens / 256 threads / 4 waves; wave = 32 rows (2 m-tiles).
// A-fragments held in VGPRs for whole kernel; A-LDS phase is unioned with
// the B1/B2/Ht phase (56.8 KB total -> 2 blocks/CU). Weight staging is
// register-prefetched one chunk ahead. Ht is XOR-swizzled (conflict-free).
// ---------------------------------------------------------------------------
__global__ __launch_bounds__(256, 2) void mlp_k(
    float* __restrict__ xio,
    const float* __restrict__ g2, const float* __restrict__ b2,
    const u16* __restrict__ fc1_wT, const float* __restrict__ fc1_b,
    const u16* __restrict__ fc2_wT, const float* __restrict__ fc2_b)
{
  // phase A: ALn u16[128][136] (34816 B)
  // phase B: B1 u16[64][136] @0 (17408) | B2 u16[128][72] @17408 (18432)
  //          | Ht u16[4][32][72] @35840 (18432)  -> union = 54272 B
  __shared__ __align__(16) char um[54272];
  __shared__ float sF1[HID];
  __shared__ float sF2[CC];
  u16* ALn = (u16*)um;
  u16* B1p = (u16*)um;
  u16* B2p = (u16*)(um + 17408);
  int tid = threadIdx.x;
  int wvid = tid >> 6, lane = tid & 63;
  int ln = lane & 15, qd = lane >> 4;
  int m0 = wvid*32;
  size_t tokbase = (size_t)blockIdx.x * 128;
  u16* Htp = (u16*)(um + 35840) + wvid*(32*72);

  sF1[tid] = fc1_b[tid]; sF1[tid+256] = fc1_b[tid+256];
  if (tid < CC) sF2[tid] = fc2_b[tid];

  // LN2 into A (128 tokens)
  float gl0 = g2[lane], gl1 = g2[lane+64];
  float bl0 = b2[lane], bl1 = b2[lane+64];
  for (int t = wvid; t < 128; t += 4) {
    const float* px = xio + (tokbase + t)*CC;
    float v0 = px[lane], v1 = px[lane+64];
    float s = v0+v1, ss = v0*v0+v1*v1;
    #pragma unroll
    for (int o = 32; o > 0; o >>= 1) { s += __shfl_xor(s,o); ss += __shfl_xor(ss,o); }
    float mu = s*(1.f/128.f), var = ss*(1.f/128.f) - mu*mu;
    float rs = rsqrtf(var + 1e-5f);
    ALn[t*136 + lane]      = f2bf((v0-mu)*rs*gl0 + bl0);
    ALn[t*136 + lane + 64] = f2bf((v1-mu)*rs*gl1 + bl1);
  }
  __syncthreads();

  // A-fragments to VGPRs (A-LDS dead afterwards)
  short8 av1[2][4];
  #pragma unroll
  for (int mt = 0; mt < 2; mt++)
    #pragma unroll
    for (int ks = 0; ks < 4; ks++)
      av1[mt][ks] = ld_frag(&ALn[(m0 + mt*16 + ln)*136 + ks*32 + qd*8]);
  __syncthreads();

  // weight staging machinery (register prefetch)
  const uint4* src1 = (const uint4*)fc1_wT;   // row = 128 u16 = 16 uint4
  const uint4* src2 = (const uint4*)fc2_wT;   // row = 512 u16 = 64 uint4
  uint4 p1[4], p2[4];
  int n1[4], q1[4], n2[4], q2[4];
  #pragma unroll
  for (int r = 0; r < 4; r++) {
    int idx = tid + r*256;
    n1[r] = idx >> 4; q1[r] = idx & 15;
    n2[r] = idx >> 3; q2[r] = idx & 7;
  }
  auto load_ch = [&](int cc){
    #pragma unroll
    for (int r = 0; r < 4; r++) {
      p1[r] = src1[(cc*64 + n1[r])*16 + q1[r]];
      p2[r] = src2[n2[r]*64 + cc*8 + q2[r]];
    }
  };
  auto store_ch = [&](){
    uint4* d1 = (uint4*)B1p; uint4* d2 = (uint4*)B2p;
    #pragma unroll
    for (int r = 0; r < 4; r++) {
      d1[n1[r]*17 + q1[r]] = p1[r];   // 136 u16 = 17 uint4
      d2[n2[r]*9  + q2[r]] = p2[r];   // 72 u16 = 9 uint4
    }
  };

  load_ch(0); store_ch();
  __syncthreads();

  floatx4 oacc[2][8];
  #pragma unroll
  for (int mt = 0; mt < 2; mt++)
    #pragma unroll
    for (int nt = 0; nt < 8; nt++) oacc[mt][nt] = (floatx4){0.f,0.f,0.f,0.f};

  for (int ch = 0; ch < 8; ch++) {
    if (ch < 7) load_ch(ch+1);   // prefetch next chunk into VGPRs

    // gemm1: h[32 x 64] = A-rows @ B1^T
    floatx4 h[2][4];
    #pragma unroll
    for (int mt = 0; mt < 2; mt++)
      #pragma unroll
      for (int nt = 0; nt < 4; nt++) h[mt][nt] = (floatx4){0.f,0.f,0.f,0.f};
    #pragma unroll
    for (int nt = 0; nt < 4; nt++) {
      short8 bv[4];
      #pragma unroll
      for (int ks = 0; ks < 4; ks++)
        bv[ks] = ld_frag(&B1p[(nt*16 + ln)*136 + ks*32 + qd*8]);
      #pragma unroll
      for (int mt = 0; mt < 2; mt++)
        #pragma unroll
        for (int ks = 0; ks < 4; ks++)
          h[mt][nt] = __builtin_amdgcn_mfma_f32_16x16x32_bf16(av1[mt][ks], bv[ks], h[mt][nt], 0, 0, 0);
    }
    // bias + GELU -> Ht (per-wave region, XOR-swizzled, D->A layout)
    #pragma unroll
    for (int mt = 0; mt < 2; mt++)
      #pragma unroll
      for (int nt = 0; nt < 4; nt++) {
        float bias = sF1[ch*64 + nt*16 + ln];
        #pragma unroll
        for (int r = 0; r < 4; r++) {
          float g = gelu_f(h[mt][nt][r] + bias);
          int row = mt*16 + qd*4 + r;
          int col = nt*16 + ln;
          Htp[row*72 + (col ^ ((row & 8) << 1))] = f2bf(g);
        }
      }
    asm volatile("s_waitcnt lgkmcnt(0)" ::: "memory");  // same-wave Ht handoff

    // gemm2: oacc[32 x 128] += Ht @ B2^T
    short8 av2[2][2];
    #pragma unroll
    for (int mt = 0; mt < 2; mt++)
      #pragma unroll
      for (int ks = 0; ks < 2; ks++) {
        int rrow = mt*16 + ln;
        int kk = ks*32 + qd*8;
        av2[mt][ks] = ld_frag(&Htp[rrow*72 + (kk ^ ((rrow & 8) << 1))]);
      }
    #pragma unroll
    for (int nt = 0; nt < 8; nt++) {
      short8 bv2[2];
      #pragma unroll
      for (int ks = 0; ks < 2; ks++)
        bv2[ks] = ld_frag(&B2p[(nt*16 + ln)*72 + ks*32 + qd*8]);
      #pragma unroll
      for (int mt = 0; mt < 2; mt++)
        #pragma unroll
        for (int ks = 0; ks < 2; ks++)
          oacc[mt][nt] = __builtin_amdgcn_mfma_f32_16x16x32_bf16(av2[mt][ks], bv2[ks], oacc[mt][nt], 0, 0, 0);
    }
    __syncthreads();             // all waves done reading B1/B2
    if (ch < 7) { store_ch(); __syncthreads(); }
  }

  // epilogue: + fc2 bias + residual, in-place
  #pragma unroll
  for (int mt = 0; mt < 2; mt++)
    #pragma unroll
    for (int r = 0; r < 4; r++) {
      size_t tok = tokbase + m0 + mt*16 + qd*4 + r;
      float* rowp = xio + tok*CC;
      #pragma unroll
      for (int nt = 0; nt < 8; nt++) {
        int n = nt*16 + ln;
        rowp[n] = rowp[n] + oacc[mt][nt][r] + sF2[n];
      }
    }
}

extern "C" void kernel_launch(void* const* d_in, const int* in_sizes, int n_in,
                              void* d_out, int out_size, void* d_ws, size_t ws_size,
                              hipStream_t stream) {
  const float* x     = (const float*)d_in[0];
  const float* g1    = (const float*)d_in[1];
  const float* b1    = (const float*)d_in[2];
  const float* sw    = (const float*)d_in[3];
  const float* sb    = (const float*)d_in[4];
  const float* g2    = (const float*)d_in[5];
  const float* b2    = (const float*)d_in[6];
  const float* fc1_w = (const float*)d_in[7];
  const float* fc1_b = (const float*)d_in[8];
  const float* fc2_w = (const float*)d_in[9];
  const float* fc2_b = (const float*)d_in[10];
  float* out = (float*)d_out;

  u16* fc1_wT = (u16*)d_ws;                  // 512*128 bf16 (131072 B)
  u16* fc2_wT = fc1_wT + HID*CC;             // 128*512 bf16 (131072 B)
  u16* swT    = fc2_wT + CC*HID;             // 4*64*68 bf16 (34816 B)

  prep_k<<<64, 256, 0, stream>>>(fc1_w, fc2_w, sw, fc1_wT, fc2_wT, swT);
  winmix_k<<<NB*81, 256, 0, stream>>>(x, g1, b1, swT, sb, out);
  mlp_k<<<(NB*HH*WW_)/128, 256, 0, stream>>>(out, g2, b2, fc1_wT, fc1_b, fc2_wT, fc2_b);
}